// Round 3
// baseline (4979.021 us; speedup 1.0000x reference)
//
#include <hip/hip_runtime.h>
#include <hip/hip_bf16.h>
#include <stdint.h>

// ---------------------------------------------------------------------------
// 2-layer LSTM (B=256, T=1024, H=256), persistent clusters, self-paced
// dataflow. R11 = R10 (barrier-free step, register staging, prefetched
// flags, shfl-transpose gate exchange) with the asm fixed:
//   - global_load modifier order: "off offset:N sc0 sc1"
//   - offset:N is 13-bit signed -> max 3072 used; 8KB blocks split across
//     two base pointers.
// Protocol semantics identical to R8 (proven): L0: L0all>=t && L1all>=t-2;
// L1: L0all>=t+1 && L1all>=t; 4-slot h/op buffers; store -> per-wave
// vmcnt(0) drain -> per-wave flag publish.
// ---------------------------------------------------------------------------

#define TT 1024
#define NC 16

typedef __attribute__((ext_vector_type(8))) short  bfrag;
typedef __attribute__((ext_vector_type(4))) float  ffrag;

__device__ __forceinline__ float sigf(float v){ return 1.f/(1.f+__expf(-v)); }
__device__ __forceinline__ float tanhfast(float v){
    v = fminf(fmaxf(v,-15.f),15.f);
    float e = __expf(2.f*v);
    return (e-1.f)/(e+1.f);
}
__device__ __forceinline__ void st32(uint32_t* p, uint32_t v){
    __hip_atomic_store(p, v, __ATOMIC_RELAXED, __HIP_MEMORY_SCOPE_AGENT);
}
__device__ __forceinline__ void stf(float* p, float v){
    __hip_atomic_store(p, v, __ATOMIC_RELAXED, __HIP_MEMORY_SCOPE_AGENT);
}
__device__ __forceinline__ void drain_vmem(){
    __asm__ volatile("s_waitcnt vmcnt(0)" ::: "memory");
}
// Issue 2 coherent flag loads, NO wait (bound later by flag_wait).
__device__ __forceinline__ void flag_prefetch(const int* pa, const int* pb,
                                              int& fa, int& fb){
    __asm__ volatile(
        "global_load_dword %0, %2, off sc0 sc1\n\t"
        "global_load_dword %1, %3, off sc0 sc1"
        : "=&v"(fa), "=&v"(fb) : "v"(pa), "v"(pb) : "memory");
}
// Bind prefetched values: vmcnt(0) with data-dependency through fa/fb.
__device__ __forceinline__ void flag_wait(int& fa, int& fb){
    __asm__ volatile("s_waitcnt vmcnt(0)" : "+v"(fa), "+v"(fb) :: "memory");
    __builtin_amdgcn_sched_barrier(0);
}
__device__ __forceinline__ void flag_load(const int* pa, const int* pb,
                                          int& fa, int& fb){
    __asm__ volatile(
        "global_load_dword %0, %2, off sc0 sc1\n\t"
        "global_load_dword %1, %3, off sc0 sc1\n\t"
        "s_waitcnt vmcnt(0)"
        : "=&v"(fa), "=&v"(fb) : "v"(pa), "v"(pb) : "memory");
}
__device__ __forceinline__ float2 ldf2_coh(const float* p1, const float* p2){
    float a, b;
    __asm__ volatile(
        "global_load_dword %0, %2, off sc0 sc1\n\t"
        "global_load_dword %1, %3, off sc0 sc1\n\t"
        "s_waitcnt vmcnt(0)"
        : "=&v"(a), "=&v"(b) : "v"(p1), "v"(p2) : "memory");
    return make_float2(a, b);
}
// 4x4 transpose across (reg index) x (lane bits 0-1):
// out[l][i] = in[(l&~3)|i][l&3].
__device__ __forceinline__ void xpose4(ffrag& a, int lane){
    float x0 = (lane&1) ? a[0] : a[1];
    float y0 = __shfl_xor(x0, 1);
    a[0] = (lane&1) ? y0 : a[0];  a[1] = (lane&1) ? a[1] : y0;
    float x1 = (lane&1) ? a[2] : a[3];
    float y1 = __shfl_xor(x1, 1);
    a[2] = (lane&1) ? y1 : a[2];  a[3] = (lane&1) ? a[3] : y1;
    float x2 = (lane&2) ? a[0] : a[2];
    float y2 = __shfl_xor(x2, 2);
    a[0] = (lane&2) ? y2 : a[0];  a[2] = (lane&2) ? a[2] : y2;
    float x3 = (lane&2) ? a[1] : a[3];
    float y3 = __shfl_xor(x3, 2);
    a[1] = (lane&2) ? y3 : a[1];  a[3] = (lane&2) ? a[3] : y3;
}

__global__ void __launch_bounds__(256, 1)
lstm_kernel(const float* __restrict__ x,
            const float* __restrict__ Wih0, const float* __restrict__ Whh0,
            const float* __restrict__ bih0, const float* __restrict__ bhh0,
            const float* __restrict__ Wih1, const float* __restrict__ Whh1,
            const float* __restrict__ bih1, const float* __restrict__ bhh1,
            const float* __restrict__ Wlin, const float* __restrict__ blin,
            float* __restrict__ out, char* __restrict__ ws)
{
    const int tid = threadIdx.x;
    const int wg  = blockIdx.x;
    const int c   = wg >> 4;
    const int j   = wg & 15;
    const bool isL0 = (j < 8);
    const int  u0   = (isL0 ? j : (j - 8)) * 32;

    // ws layout:
    //   flags: 16 clusters x 64 wave-flags x 128B = 128 KB          [0)
    //   h0:    [4 slots][NC][8 prod][16 rows][32 units bf16] 512 KB [131072)
    //   h1:    same, 512 KB                                         [655360)
    //   op:    [4][NC][32 partials][16 rows] fp32, 128 KB           [1179648)
    int* flagbase = (int*)(ws + (size_t)c * 8192);
    uint32_t* h0w = (uint32_t*)(ws + 131072);
    uint32_t* h1w = h0w + 4 * NC * 8 * 256;
    float*    op  = (float*)(h1w + 4 * NC * 8 * 256);

    // ---- LDS: Wt (64KB) + Wt2/xs (64KB, aliased) ----
    __shared__ __attribute__((aligned(16))) char S[131072];
    __hip_bfloat16* Wt  = (__hip_bfloat16*)S;            // L0: Whh0; L1: Wih1
    __hip_bfloat16* Wt2 = (__hip_bfloat16*)(S + 65536);  // L1: Whh1
    float*          xs  = (float*)(S + 65536);           // L0: x fp32 [t][16]

    const int lane = tid & 63, wave = tid >> 6;
    const int q_l  = (lane >> 2) & 3;
    const int g_l  = lane & 3;
    const int rg   = lane >> 4;
    const int row  = rg * 4 + g_l;          // batch row within cluster (0..15)
    const int u_e  = wave * 8 + q_l * 2;    // local unit (even), u_o = u_e+1

    // ---- one-time init ----
    {
        // W pack with column permutation: col n -> ntile=n>>4, cc=n&15,
        // q=cc>>2, g=cc&3, unit = 8*(ntile>>1)+2q+(ntile&1), row g*256+u0+unit.
        const float* Wsrc = isL0 ? Whh0 : Wih1;
        for (int i = tid; i < 128 * 256; i += 256) {
            int n = i >> 8, k = i & 255;
            int ntile = n >> 4, cc = n & 15, q = cc >> 2, g = cc & 3;
            int unit = 8 * (ntile >> 1) + 2 * q + (ntile & 1);
            int r = g * 256 + u0 + unit;
            int ln = (n & 15) | (((k >> 3) & 3) << 4);
            int toff = (ntile * 8 + (k >> 5)) * 1024 + ln * 16 + (k & 7) * 2;
            *(__hip_bfloat16*)((char*)Wt + toff) = __float2bfloat16(Wsrc[r * 256 + k]);
            if (!isL0)
                *(__hip_bfloat16*)((char*)Wt2 + toff) = __float2bfloat16(Whh1[r * 256 + k]);
        }
        if (isL0) {
            for (int i = tid; i < 16 * 1024; i += 256)   // xs[t][16 rows]
                xs[i] = x[(c * 16 + (i & 15)) * TT + (i >> 4)];
        }
        // zero own h(-1) slot-3 block
        uint32_t* z = isL0 ? (h0w + ((3 * NC + c) * 8 + j) * 256)
                           : (h1w + ((3 * NC + c) * 8 + (j - 8)) * 256);
        st32(z + tid, 0u);
    }
    // per-lane constants (regs): bias, x-weights / Wlin
    float be0,be1,be2,be3, bo0,bo1,bo2,bo3;
    float we0=0,we1=0,we2=0,we3=0, wo0=0,wo1=0,wo2=0,wo3=0;
    float wle=0, wlo=0;
    {
        const float* bi = isL0 ? bih0 : bih1;
        const float* bh = isL0 ? bhh0 : bhh1;
        int r0 = u0 + u_e;
        be0 = bi[r0] + bh[r0];               bo0 = bi[r0+1] + bh[r0+1];
        be1 = bi[256+r0] + bh[256+r0];       bo1 = bi[256+r0+1] + bh[256+r0+1];
        be2 = bi[512+r0] + bh[512+r0];       bo2 = bi[512+r0+1] + bh[512+r0+1];
        be3 = bi[768+r0] + bh[768+r0];       bo3 = bi[768+r0+1] + bh[768+r0+1];
        if (isL0) {
            we0 = Wih0[r0];     wo0 = Wih0[r0+1];
            we1 = Wih0[256+r0]; wo1 = Wih0[256+r0+1];
            we2 = Wih0[512+r0]; wo2 = Wih0[512+r0+1];
            we3 = Wih0[768+r0]; wo3 = Wih0[768+r0+1];
        } else {
            wle = Wlin[u0 + u_e]; wlo = Wlin[u0 + u_e + 1];
        }
    }
    const float blin_r = blin[0];
    drain_vmem();
    __syncthreads();                         // LDS W ready; zeroes drained
    if (lane == 0) st32((uint32_t*)(flagbase + (j * 4 + wave) * 32), 0u);

    // flag geometry: per-lane coverage of all 32 wave-flags of each layer
    const int* pa = flagbase + (lane & 31) * 32;          // L0 set
    const int* pb = flagbase + (32 + (lane & 31)) * 32;   // L1 set
    int* myflag = (int*)(flagbase + (j * 4 + wave) * 32);
    int fa = -1, fb = -1;                    // force a real read at t=0

    // Wt bases for this wave's n-tiles
    const char* wb0 = (const char*)Wt + (wave * 2) * 8192 + lane * 16;
    const char* wb1 = wb0 + 8192;
    const char* wc0 = (const char*)Wt2 + (wave * 2) * 8192 + lane * 16;
    const char* wc1 = wc0 + 8192;
    const int lnoff = (lane & 15) * 64 + (lane >> 4) * 16;  // block byte offset

    float c0a = 0.f, c0b = 0.f;

    if (isL0) {
        for (int t = 0; t < TT; ++t) {
            flag_wait(fa, fb);
            if (!__all((fa >= t) && (fb >= t - 2))) {
                for (;;) {
                    flag_load(pa, pb, fa, fb);
                    if (__all((fa >= t) && (fb >= t - 2))) break;
                    __builtin_amdgcn_s_sleep(1);
                }
            }
            // stage all 8 producer blocks of h0(t-1) into registers
            const char* hba = (const char*)(h0w + ((((t + 3) & 3) * NC + c) * 8) * 256) + lnoff;
            const char* hbb = hba + 4096;
            bfrag H[8];
            __asm__ volatile(
                "global_load_dwordx4 %0, %8, off sc0 sc1\n\t"
                "global_load_dwordx4 %1, %8, off offset:1024 sc0 sc1\n\t"
                "global_load_dwordx4 %2, %8, off offset:2048 sc0 sc1\n\t"
                "global_load_dwordx4 %3, %8, off offset:3072 sc0 sc1\n\t"
                "global_load_dwordx4 %4, %9, off sc0 sc1\n\t"
                "global_load_dwordx4 %5, %9, off offset:1024 sc0 sc1\n\t"
                "global_load_dwordx4 %6, %9, off offset:2048 sc0 sc1\n\t"
                "global_load_dwordx4 %7, %9, off offset:3072 sc0 sc1\n\t"
                "s_waitcnt vmcnt(0)"
                : "=&v"(H[0]), "=&v"(H[1]), "=&v"(H[2]), "=&v"(H[3]),
                  "=&v"(H[4]), "=&v"(H[5]), "=&v"(H[6]), "=&v"(H[7])
                : "v"(hba), "v"(hbb) : "memory");

            ffrag a0 = {0.f,0.f,0.f,0.f}, a1 = {0.f,0.f,0.f,0.f};
            #pragma unroll
            for (int kt = 0; kt < 8; ++kt) {
                bfrag b0 = *(const bfrag*)(wb0 + kt * 1024);
                bfrag b1 = *(const bfrag*)(wb1 + kt * 1024);
                a0 = __builtin_amdgcn_mfma_f32_16x16x32_bf16(H[kt], b0, a0, 0, 0, 0);
                a1 = __builtin_amdgcn_mfma_f32_16x16x32_bf16(H[kt], b1, a1, 0, 0, 0);
            }
            xpose4(a0, lane);
            xpose4(a1, lane);

            float xv = xs[t * 16 + row];
            float iv = a0[0] + fmaf(xv, we0, be0);
            float fv = a0[1] + fmaf(xv, we1, be1);
            float gv = a0[2] + fmaf(xv, we2, be2);
            float ov = a0[3] + fmaf(xv, we3, be3);
            c0a = sigf(fv) * c0a + sigf(iv) * tanhfast(gv);
            float hn0 = sigf(ov) * tanhfast(c0a);
            iv = a1[0] + fmaf(xv, wo0, bo0);
            fv = a1[1] + fmaf(xv, wo1, bo1);
            gv = a1[2] + fmaf(xv, wo2, bo2);
            ov = a1[3] + fmaf(xv, wo3, bo3);
            c0b = sigf(fv) * c0b + sigf(iv) * tanhfast(gv);
            float hn1 = sigf(ov) * tanhfast(c0b);

            __hip_bfloat16 hb0 = __float2bfloat16(hn0), hb1 = __float2bfloat16(hn1);
            uint32_t pk = ((uint32_t)(*(uint16_t*)&hb1) << 16) | (uint32_t)(*(uint16_t*)&hb0);

            st32(h0w + (((t & 3) * NC + c) * 8 + j) * 256 + row * 16 + wave * 4 + q_l, pk);
            drain_vmem();                    // per-wave: h at coherence point
            if (lane == 0) st32((uint32_t*)myflag, (uint32_t)(t + 1));
            flag_prefetch(pa, pb, fa, fb);   // sample AFTER publish (fresh)

            // distributed out-reduce, off the critical path (guard L1>=t-2
            // established at step top; slot safe until our flag t+2).
            if (t >= 3 && j == ((t - 3) & 7)) {
                int col = t - 3, slot = col & 3;
                const float* o1 = op + (((slot * NC + c) * 32) + (tid & 15)) * 16 + (tid >> 4);
                float2 vv = ldf2_coh(o1, o1 + 256);
                float v = vv.x + vv.y;
                v += __shfl_down(v, 8, 16);
                v += __shfl_down(v, 4, 16);
                v += __shfl_down(v, 2, 16);
                v += __shfl_down(v, 1, 16);
                if ((tid & 15) == 0) out[(c * 16 + (tid >> 4)) * TT + col] = v + blin_r;
            }
        }
    } else {
        for (int t = 0; t < TT; ++t) {
            flag_wait(fa, fb);
            if (!__all((fa >= t + 1) && (fb >= t))) {
                for (;;) {
                    flag_load(pa, pb, fa, fb);
                    if (__all((fa >= t + 1) && (fb >= t))) break;
                    __builtin_amdgcn_s_sleep(1);
                }
            }
            const char* h1a = (const char*)(h1w + ((((t + 3) & 3) * NC + c) * 8) * 256) + lnoff;
            const char* h1b = h1a + 4096;
            const char* h0a = (const char*)(h0w + (((t & 3) * NC + c) * 8) * 256) + lnoff;
            const char* h0b = h0a + 4096;
            bfrag H1[8], H0[8];
            __asm__ volatile(
                "global_load_dwordx4 %0,  %16, off sc0 sc1\n\t"
                "global_load_dwordx4 %1,  %16, off offset:1024 sc0 sc1\n\t"
                "global_load_dwordx4 %2,  %16, off offset:2048 sc0 sc1\n\t"
                "global_load_dwordx4 %3,  %16, off offset:3072 sc0 sc1\n\t"
                "global_load_dwordx4 %4,  %17, off sc0 sc1\n\t"
                "global_load_dwordx4 %5,  %17, off offset:1024 sc0 sc1\n\t"
                "global_load_dwordx4 %6,  %17, off offset:2048 sc0 sc1\n\t"
                "global_load_dwordx4 %7,  %17, off offset:3072 sc0 sc1\n\t"
                "global_load_dwordx4 %8,  %18, off sc0 sc1\n\t"
                "global_load_dwordx4 %9,  %18, off offset:1024 sc0 sc1\n\t"
                "global_load_dwordx4 %10, %18, off offset:2048 sc0 sc1\n\t"
                "global_load_dwordx4 %11, %18, off offset:3072 sc0 sc1\n\t"
                "global_load_dwordx4 %12, %19, off sc0 sc1\n\t"
                "global_load_dwordx4 %13, %19, off offset:1024 sc0 sc1\n\t"
                "global_load_dwordx4 %14, %19, off offset:2048 sc0 sc1\n\t"
                "global_load_dwordx4 %15, %19, off offset:3072 sc0 sc1\n\t"
                "s_waitcnt vmcnt(0)"
                : "=&v"(H1[0]), "=&v"(H1[1]), "=&v"(H1[2]), "=&v"(H1[3]),
                  "=&v"(H1[4]), "=&v"(H1[5]), "=&v"(H1[6]), "=&v"(H1[7]),
                  "=&v"(H0[0]), "=&v"(H0[1]), "=&v"(H0[2]), "=&v"(H0[3]),
                  "=&v"(H0[4]), "=&v"(H0[5]), "=&v"(H0[6]), "=&v"(H0[7])
                : "v"(h1a), "v"(h1b), "v"(h0a), "v"(h0b) : "memory");

            ffrag a0 = {0.f,0.f,0.f,0.f}, a1 = {0.f,0.f,0.f,0.f};
            #pragma unroll
            for (int kt = 0; kt < 8; ++kt) {        // h1(t-1) @ Whh1
                bfrag b0 = *(const bfrag*)(wc0 + kt * 1024);
                bfrag b1 = *(const bfrag*)(wc1 + kt * 1024);
                a0 = __builtin_amdgcn_mfma_f32_16x16x32_bf16(H1[kt], b0, a0, 0, 0, 0);
                a1 = __builtin_amdgcn_mfma_f32_16x16x32_bf16(H1[kt], b1, a1, 0, 0, 0);
            }
            #pragma unroll
            for (int kt = 0; kt < 8; ++kt) {        // += h0(t) @ Wih1
                bfrag b0 = *(const bfrag*)(wb0 + kt * 1024);
                bfrag b1 = *(const bfrag*)(wb1 + kt * 1024);
                a0 = __builtin_amdgcn_mfma_f32_16x16x32_bf16(H0[kt], b0, a0, 0, 0, 0);
                a1 = __builtin_amdgcn_mfma_f32_16x16x32_bf16(H0[kt], b1, a1, 0, 0, 0);
            }
            xpose4(a0, lane);
            xpose4(a1, lane);

            float iv = a0[0] + be0, fv = a0[1] + be1;
            float gv = a0[2] + be2, ov = a0[3] + be3;
            c0a = sigf(fv) * c0a + sigf(iv) * tanhfast(gv);
            float hn0 = sigf(ov) * tanhfast(c0a);
            iv = a1[0] + bo0; fv = a1[1] + bo1;
            gv = a1[2] + bo2; ov = a1[3] + bo3;
            c0b = sigf(fv) * c0b + sigf(iv) * tanhfast(gv);
            float hn1 = sigf(ov) * tanhfast(c0b);

            __hip_bfloat16 hb0 = __float2bfloat16(hn0), hb1 = __float2bfloat16(hn1);
            uint32_t pk = ((uint32_t)(*(uint16_t*)&hb1) << 16) | (uint32_t)(*(uint16_t*)&hb0);

            // out partial for column t: reduce over q (lane bits 2-3)
            float pv = hn0 * wle + hn1 * wlo;
            pv += __shfl_xor(pv, 4);
            pv += __shfl_xor(pv, 8);

            st32(h1w + (((t & 3) * NC + c) * 8 + (j - 8)) * 256 + row * 16 + wave * 4 + q_l, pk);
            if ((lane & 12) == 0)
                stf(op + ((((t & 3) * NC + c) * 32) + (j - 8) * 4 + wave) * 16 + row, pv);
            drain_vmem();                    // per-wave: h + op at coherence pt
            if (lane == 0) st32((uint32_t*)myflag, (uint32_t)(t + 1));
            flag_prefetch(pa, pb, fa, fb);   // sample AFTER publish (fresh)
        }
    }

    drain_vmem();

    // tail: columns TT-3..TT-1 by L0 WGs 5,6,7 (need all L1 waves >= TT)
    if (isL0 && j >= 5) {
        flag_wait(fa, fb);
        while (!__all(fb >= TT)) {
            flag_load(pa, pb, fa, fb);
            if (__all(fb >= TT)) break;
            __builtin_amdgcn_s_sleep(1);
        }
        int col = TT - 8 + j, slot = col & 3;
        const float* o1 = op + (((slot * NC + c) * 32) + (tid & 15)) * 16 + (tid >> 4);
        float2 vv = ldf2_coh(o1, o1 + 256);
        float v = vv.x + vv.y;
        v += __shfl_down(v, 8, 16);
        v += __shfl_down(v, 4, 16);
        v += __shfl_down(v, 2, 16);
        v += __shfl_down(v, 1, 16);
        if ((tid & 15) == 0) out[(c * 16 + (tid >> 4)) * TT + col] = v + blin_r;
    }
}

extern "C" void kernel_launch(void* const* d_in, const int* in_sizes, int n_in,
                              void* d_out, int out_size, void* d_ws, size_t ws_size,
                              hipStream_t stream)
{
    const float* x    = (const float*)d_in[0];
    const float* Wih0 = (const float*)d_in[1];
    const float* Whh0 = (const float*)d_in[2];
    const float* bih0 = (const float*)d_in[3];
    const float* bhh0 = (const float*)d_in[4];
    const float* Wih1 = (const float*)d_in[5];
    const float* Whh1 = (const float*)d_in[6];
    const float* bih1 = (const float*)d_in[7];
    const float* bhh1 = (const float*)d_in[8];
    const float* Wlin = (const float*)d_in[9];
    const float* blin = (const float*)d_in[10];
    float* out = (float*)d_out;
    char* ws   = (char*)d_ws;

    // 256 blocks x 256 threads, 1 block/CU -> all co-resident (spin-safe).
    lstm_kernel<<<dim3(256), dim3(256), 0, stream>>>(
        x, Wih0, Whh0, bih0, bhh0, Wih1, Whh1, bih1, bhh1, Wlin, blin, out, ws);
}

// Round 4
// 3284.205 us; speedup vs baseline: 1.5161x; 1.5161x over previous
//
#include <hip/hip_runtime.h>
#include <hip/hip_bf16.h>
#include <stdint.h>

// ---------------------------------------------------------------------------
// 2-layer LSTM (B=256, T=1024, H=256), persistent clusters, self-paced
// dataflow. R12 = R8 skeleton (fused 4-flag broadcast poll, global_load_lds
// staging, per-WG flags/private lines, 4-slot buffers) + three low-risk
// grafts:
//  1. xpose4 shuffle gate exchange (R11-proven): W columns permuted at init
//     so each 4-lane group owns the 4 gates of one unit; gbuf LDS round-trip
//     (2 barriers + ~1M bank conflicts) deleted; bias/Wih0/Wlin in regs.
//  2. Distributed out-reduce moved AFTER flag publish (guard L1>=t-2 is
//     established at step top; op slot (t-3)&3 is only overwritten after L1
//     sees our flag t+2, one full step later).
//  3. Flag prefetch fused into the store drain: the 4 broadcast flag loads
//     are issued before drain_vmem(); the drain's vmcnt(0) returns them with
//     the store acks. Next step's check is free on hit (own flag skipped -
//     trivially satisfied); on miss falls into R8's exact poll loop.
// R11 post-mortem: per-wave register staging + per-lane flag fan-out
// multiplied coherent IC traffic (FETCH +35%, 64 lines/poll) and inflated
// every RT -> 4979us. R12 keeps one staging op per WG, broadcast flag lines.
// ---------------------------------------------------------------------------

#define TT 1024
#define NC 16

typedef __attribute__((ext_vector_type(8))) short  bfrag;
typedef __attribute__((ext_vector_type(4))) float  ffrag;

__device__ __forceinline__ float sigf(float v){ return 1.f/(1.f+__expf(-v)); }
__device__ __forceinline__ float tanhfast(float v){
    v = fminf(fmaxf(v,-15.f),15.f);
    float e = __expf(2.f*v);
    return (e-1.f)/(e+1.f);
}
__device__ __forceinline__ void st32(uint32_t* p, uint32_t v){
    __hip_atomic_store(p, v, __ATOMIC_RELAXED, __HIP_MEMORY_SCOPE_AGENT);
}
__device__ __forceinline__ void st64(unsigned long long* p, unsigned long long v){
    __hip_atomic_store(p, v, __ATOMIC_RELAXED, __HIP_MEMORY_SCOPE_AGENT);
}
__device__ __forceinline__ void stf(float* p, float v){
    __hip_atomic_store(p, v, __ATOMIC_RELAXED, __HIP_MEMORY_SCOPE_AGENT);
}
__device__ __forceinline__ void drain_vmem(){
    __asm__ volatile("s_waitcnt vmcnt(0)" ::: "memory");
}
__device__ __forceinline__ float2 ldf2_coh(const float* p1, const float* p2){
    float a, b;
    __asm__ volatile(
        "global_load_dword %0, %2, off sc0 sc1\n\t"
        "global_load_dword %1, %3, off sc0 sc1\n\t"
        "s_waitcnt vmcnt(0)"
        : "=&v"(a), "=&v"(b) : "v"(p1), "v"(p2) : "memory");
    return make_float2(a, b);
}
// Issue 4 broadcast flag loads, NO wait (completed by the following drain).
__device__ __forceinline__ void prefetch4(const int* fa, const int* fb,
                                          const int* fc, const int* fd,
                                          int& va, int& vb, int& vc, int& vd){
    __asm__ volatile(
        "global_load_dword %0, %4, off sc0 sc1\n\t"
        "global_load_dword %1, %5, off sc0 sc1\n\t"
        "global_load_dword %2, %6, off sc0 sc1\n\t"
        "global_load_dword %3, %7, off sc0 sc1"
        : "=&v"(va), "=&v"(vb), "=&v"(vc), "=&v"(vd)
        : "v"(fa), "v"(fb), "v"(fc), "v"(fd) : "memory");
}
// Fast-path check on prefetched values (skX: skip own flag - trivially ok),
// else R8's exact poll loop (fresh 4-line batch, one vmcnt, sleep between).
__device__ __forceinline__ void wave_poll_pf(const int* fa, const int* fb,
                                             const int* fc, const int* fd,
                                             int tgtA, int tgtB,
                                             bool skA, bool skB, bool skC, bool skD,
                                             int& va, int& vb, int& vc, int& vd){
    __asm__ volatile("s_waitcnt vmcnt(0)"
                     : "+v"(va), "+v"(vb), "+v"(vc), "+v"(vd) :: "memory");
    __builtin_amdgcn_sched_barrier(0);
    if ((skA || va >= tgtA) && (skB || vb >= tgtA) &&
        (skC || vc >= tgtB) && (skD || vd >= tgtB)) return;
    for (;;) {
        __asm__ volatile(
            "global_load_dword %0, %4, off sc0 sc1\n\t"
            "global_load_dword %1, %5, off sc0 sc1\n\t"
            "global_load_dword %2, %6, off sc0 sc1\n\t"
            "global_load_dword %3, %7, off sc0 sc1\n\t"
            "s_waitcnt vmcnt(0)"
            : "=&v"(va), "=&v"(vb), "=&v"(vc), "=&v"(vd)
            : "v"(fa), "v"(fb), "v"(fc), "v"(fd) : "memory");
        if (va >= tgtA && vb >= tgtA && vc >= tgtB && vd >= tgtB) return;
        __builtin_amdgcn_s_sleep(1);
    }
}
// Direct-to-LDS stage of one 16x32 bf16 A-tile from a per-producer 1KB block.
__device__ __forceinline__ void stage_tile(uint32_t* ldsbase, const uint32_t* hblocks,
                                           int kt, int lane){
    const uint32_t* g = hblocks + (kt << 8) + ((lane & 15) << 4) + ((lane >> 4) << 2);
    uint32_t* l = ldsbase + (kt << 8);
    __builtin_amdgcn_global_load_lds(
        (const __attribute__((address_space(1))) uint32_t*)(uintptr_t)g,
        (__attribute__((address_space(3))) uint32_t*)(uint32_t)(uintptr_t)l,
        16, 0, 0x11);
}
// 4x4 transpose across (reg index) x (lane bits 0-1) - R11-proven.
__device__ __forceinline__ void xpose4(ffrag& a, int lane){
    float x0 = (lane&1) ? a[0] : a[1];
    float y0 = __shfl_xor(x0, 1);
    a[0] = (lane&1) ? y0 : a[0];  a[1] = (lane&1) ? a[1] : y0;
    float x1 = (lane&1) ? a[2] : a[3];
    float y1 = __shfl_xor(x1, 1);
    a[2] = (lane&1) ? y1 : a[2];  a[3] = (lane&1) ? a[3] : y1;
    float x2 = (lane&2) ? a[0] : a[2];
    float y2 = __shfl_xor(x2, 2);
    a[0] = (lane&2) ? y2 : a[0];  a[2] = (lane&2) ? a[2] : y2;
    float x3 = (lane&2) ? a[1] : a[3];
    float y3 = __shfl_xor(x3, 2);
    a[1] = (lane&2) ? y3 : a[1];  a[3] = (lane&2) ? a[3] : y3;
}

__global__ void __launch_bounds__(256, 1)
lstm_kernel(const float* __restrict__ x,
            const float* __restrict__ Wih0, const float* __restrict__ Whh0,
            const float* __restrict__ bih0, const float* __restrict__ bhh0,
            const float* __restrict__ Wih1, const float* __restrict__ Whh1,
            const float* __restrict__ bih1, const float* __restrict__ bhh1,
            const float* __restrict__ Wlin, const float* __restrict__ blin,
            float* __restrict__ out, char* __restrict__ ws)
{
    const int tid = threadIdx.x;
    const int wg  = blockIdx.x;
    const int c   = wg >> 4;
    const int j   = wg & 15;
    const bool isL0 = (j < 8);
    const int  u0   = (isL0 ? j : (j - 8)) * 32;

    // ws: flags 16 clusters x 16 WGs x 128B = 64KB | h0 512KB | h1 512KB |
    //     op [4][NC][32 partials][16 rows] fp32 = 128KB
    int* flagbase = (int*)(ws + c * 4096);
    uint32_t* h0w = (uint32_t*)(ws + 65536);
    uint32_t* h1w = h0w + 4 * NC * 8 * 256;
    float*    op  = (float*)(h1w + 4 * NC * 8 * 256);

    // LDS: Wt 64KB | Wt2/xs 64KB (aliased) | hs0 8KB | hs1 8KB
    __shared__ __attribute__((aligned(16))) char S[147456];
    __hip_bfloat16* Wt  = (__hip_bfloat16*)S;            // L0: Whh0; L1: Wih1
    __hip_bfloat16* Wt2 = (__hip_bfloat16*)(S + 65536);  // L1: Whh1
    float*          xs  = (float*)(S + 65536);           // L0: x fp32 [t][16]
    uint32_t*       hs0 = (uint32_t*)(S + 131072);
    uint32_t*       hs1 = (uint32_t*)(S + 139264);

    const int lane = tid & 63, wave = tid >> 6;
    const int q_l  = (lane >> 2) & 3;
    const int g_l  = lane & 3;
    const int rg   = lane >> 4;
    const int row  = rg * 4 + g_l;          // batch row within cluster (0..15)
    const int u_e  = wave * 8 + q_l * 2;    // local unit (even), u_o = u_e+1

    // ---- one-time init (R11-proven W permutation pack) ----
    {
        const float* Wsrc = isL0 ? Whh0 : Wih1;
        for (int i = tid; i < 128 * 256; i += 256) {
            int n = i >> 8, k = i & 255;
            int ntile = n >> 4, cc = n & 15, q = cc >> 2, g = cc & 3;
            int unit = 8 * (ntile >> 1) + 2 * q + (ntile & 1);
            int r = g * 256 + u0 + unit;
            int ln = (n & 15) | (((k >> 3) & 3) << 4);
            int toff = (ntile * 8 + (k >> 5)) * 1024 + ln * 16 + (k & 7) * 2;
            *(__hip_bfloat16*)((char*)Wt + toff) = __float2bfloat16(Wsrc[r * 256 + k]);
            if (!isL0)
                *(__hip_bfloat16*)((char*)Wt2 + toff) = __float2bfloat16(Whh1[r * 256 + k]);
        }
        if (isL0) {
            for (int i = tid; i < 16 * 1024; i += 256)   // xs[t][16 rows]
                xs[i] = x[(c * 16 + (i & 15)) * TT + (i >> 4)];
        }
        // zero own h(-1) slot-3 block (redundant w/ harness memset, harmless)
        uint32_t* z = isL0 ? (h0w + ((3 * NC + c) * 8 + j) * 256)
                           : (h1w + ((3 * NC + c) * 8 + (j - 8)) * 256);
        st32(z + tid, 0u);
    }
    // per-lane constants (regs): bias, x-weights / Wlin (R11-proven)
    float be0,be1,be2,be3, bo0,bo1,bo2,bo3;
    float we0=0,we1=0,we2=0,we3=0, wo0=0,wo1=0,wo2=0,wo3=0;
    float wle=0, wlo=0;
    {
        const float* bi = isL0 ? bih0 : bih1;
        const float* bh = isL0 ? bhh0 : bhh1;
        int r0 = u0 + u_e;
        be0 = bi[r0] + bh[r0];               bo0 = bi[r0+1] + bh[r0+1];
        be1 = bi[256+r0] + bh[256+r0];       bo1 = bi[256+r0+1] + bh[256+r0+1];
        be2 = bi[512+r0] + bh[512+r0];       bo2 = bi[512+r0+1] + bh[512+r0+1];
        be3 = bi[768+r0] + bh[768+r0];       bo3 = bi[768+r0+1] + bh[768+r0+1];
        if (isL0) {
            we0 = Wih0[r0];     wo0 = Wih0[r0+1];
            we1 = Wih0[256+r0]; wo1 = Wih0[256+r0+1];
            we2 = Wih0[512+r0]; wo2 = Wih0[512+r0+1];
            we3 = Wih0[768+r0]; wo3 = Wih0[768+r0+1];
        } else {
            wle = Wlin[u0 + u_e]; wlo = Wlin[u0 + u_e + 1];
        }
    }
    const float blin_r = blin[0];
    drain_vmem();
    __syncthreads();
    if (tid == 0) st32((uint32_t*)(flagbase + j * 32), 0u);

    // my 4 dependency flags, each on a private 128B line (R8 geometry)
    const int* fL0a = flagbase + (wave)      * 32;
    const int* fL0b = flagbase + (wave + 4)  * 32;
    const int* fL1a = flagbase + (8 + wave)  * 32;
    const int* fL1b = flagbase + (12 + wave) * 32;
    int* myflag = (int*)(flagbase + j * 32);
    // own-flag membership in the polled set (fast-path skip: trivially ok)
    const bool skA = isL0 && (j == wave);
    const bool skB = isL0 && (j == wave + 4);
    const bool skC = (!isL0) && (j - 8 == wave);
    const bool skD = (!isL0) && (j - 8 == wave + 4);
    int va = -1000, vb = -1000, vc = -1000, vd = -1000;  // force poll at t=0

    // Wt bases for this wave's 2 n-tiles
    const char* wb0 = (const char*)Wt + (wave * 2) * 8192 + lane * 16;
    const char* wb1 = wb0 + 8192;
    const char* wc0 = (const char*)Wt2 + (wave * 2) * 8192 + lane * 16;
    const char* wc1 = wc0 + 8192;

    float c0a = 0.f, c0b = 0.f;

    if (isL0) {
        for (int t = 0; t < TT; ++t) {
            // data: peers' h0(t-1) [L0 >= t]; overwrite-safety [L1 >= t-2]
            wave_poll_pf(fL0a, fL0b, fL1a, fL1b, t, t - 2,
                         skA, skB, false, false, va, vb, vc, vd);
            const uint32_t* src = h0w + (((t + 3) & 3) * NC + c) * 8 * 256;  // h0(t-1)
            stage_tile(hs0, src, wave, lane);
            stage_tile(hs0, src, wave + 4, lane);
            __syncthreads();

            ffrag a0 = {0.f,0.f,0.f,0.f}, a1 = {0.f,0.f,0.f,0.f};
            #pragma unroll
            for (int kt = 0; kt < 8; ++kt) {
                bfrag av = *(const bfrag*)((const char*)hs0 + kt * 1024 + lane * 16);
                bfrag b0 = *(const bfrag*)(wb0 + kt * 1024);
                bfrag b1 = *(const bfrag*)(wb1 + kt * 1024);
                a0 = __builtin_amdgcn_mfma_f32_16x16x32_bf16(av, b0, a0, 0, 0, 0);
                a1 = __builtin_amdgcn_mfma_f32_16x16x32_bf16(av, b1, a1, 0, 0, 0);
            }
            xpose4(a0, lane);
            xpose4(a1, lane);

            float xv = xs[t * 16 + row];
            float iv = a0[0] + fmaf(xv, we0, be0);
            float fv = a0[1] + fmaf(xv, we1, be1);
            float gv = a0[2] + fmaf(xv, we2, be2);
            float ov = a0[3] + fmaf(xv, we3, be3);
            c0a = sigf(fv) * c0a + sigf(iv) * tanhfast(gv);
            float hn0 = sigf(ov) * tanhfast(c0a);
            iv = a1[0] + fmaf(xv, wo0, bo0);
            fv = a1[1] + fmaf(xv, wo1, bo1);
            gv = a1[2] + fmaf(xv, wo2, bo2);
            ov = a1[3] + fmaf(xv, wo3, bo3);
            c0b = sigf(fv) * c0b + sigf(iv) * tanhfast(gv);
            float hn1 = sigf(ov) * tanhfast(c0b);

            __hip_bfloat16 hb0 = __float2bfloat16(hn0), hb1 = __float2bfloat16(hn1);
            uint32_t pk = ((uint32_t)(*(uint16_t*)&hb1) << 16) | (uint32_t)(*(uint16_t*)&hb0);
            uint32_t nb = __shfl_down(pk, 4);     // q+1 partner (same row)
            if ((q_l & 1) == 0) {
                unsigned long long v = (unsigned long long)pk |
                                       ((unsigned long long)nb << 32);
                st64((unsigned long long*)
                     (h0w + (((t & 3) * NC + c) * 8 + j) * 256 + row * 16 + wave * 4 + q_l), v);
            }
            prefetch4(fL0a, fL0b, fL1a, fL1b, va, vb, vc, vd);  // ride the drain
            drain_vmem();                    // per-wave: h acks + flags back
            __syncthreads();                 // all waves' slices ack'd
            if (tid == 0) st32((uint32_t*)myflag, (uint32_t)(t + 1));

            // distributed out-reduce: column t-3, OFF the critical path
            if (t >= 3 && j == ((t - 3) & 7)) {
                int col = t - 3, slot = col & 3;
                const float* o1 = op + (((slot * NC + c) * 32) + (tid & 15)) * 16 + (tid >> 4);
                float2 vv = ldf2_coh(o1, o1 + 256);
                float v = vv.x + vv.y;
                v += __shfl_down(v, 8, 16);
                v += __shfl_down(v, 4, 16);
                v += __shfl_down(v, 2, 16);
                v += __shfl_down(v, 1, 16);
                if ((tid & 15) == 0) out[(c * 16 + (tid >> 4)) * TT + col] = v + blin_r;
            }
        }
    } else {
        for (int t = 0; t < TT; ++t) {
            // data: h0(t) [L0 >= t+1] and peers' h1(t-1) [L1 >= t]
            wave_poll_pf(fL0a, fL0b, fL1a, fL1b, t + 1, t,
                         false, false, skC, skD, va, vb, vc, vd);
            const uint32_t* s0 = h0w + ((t & 3) * NC + c) * 8 * 256;         // h0(t)
            const uint32_t* s1 = h1w + (((t + 3) & 3) * NC + c) * 8 * 256;   // h1(t-1)
            stage_tile(hs0, s0, wave, lane);
            stage_tile(hs0, s0, wave + 4, lane);
            stage_tile(hs1, s1, wave, lane);
            stage_tile(hs1, s1, wave + 4, lane);
            __syncthreads();

            ffrag a0 = {0.f,0.f,0.f,0.f}, a1 = {0.f,0.f,0.f,0.f};
            #pragma unroll
            for (int kt = 0; kt < 8; ++kt) {       // h0(t) @ Wih1
                bfrag av = *(const bfrag*)((const char*)hs0 + kt * 1024 + lane * 16);
                bfrag b0 = *(const bfrag*)(wb0 + kt * 1024);
                bfrag b1 = *(const bfrag*)(wb1 + kt * 1024);
                a0 = __builtin_amdgcn_mfma_f32_16x16x32_bf16(av, b0, a0, 0, 0, 0);
                a1 = __builtin_amdgcn_mfma_f32_16x16x32_bf16(av, b1, a1, 0, 0, 0);
            }
            #pragma unroll
            for (int kt = 0; kt < 8; ++kt) {       // += h1(t-1) @ Whh1
                bfrag av = *(const bfrag*)((const char*)hs1 + kt * 1024 + lane * 16);
                bfrag b0 = *(const bfrag*)(wc0 + kt * 1024);
                bfrag b1 = *(const bfrag*)(wc1 + kt * 1024);
                a0 = __builtin_amdgcn_mfma_f32_16x16x32_bf16(av, b0, a0, 0, 0, 0);
                a1 = __builtin_amdgcn_mfma_f32_16x16x32_bf16(av, b1, a1, 0, 0, 0);
            }
            xpose4(a0, lane);
            xpose4(a1, lane);

            float iv = a0[0] + be0, fv = a0[1] + be1;
            float gv = a0[2] + be2, ov = a0[3] + be3;
            c0a = sigf(fv) * c0a + sigf(iv) * tanhfast(gv);
            float hn0 = sigf(ov) * tanhfast(c0a);
            iv = a1[0] + bo0; fv = a1[1] + bo1;
            gv = a1[2] + bo2; ov = a1[3] + bo3;
            c0b = sigf(fv) * c0b + sigf(iv) * tanhfast(gv);
            float hn1 = sigf(ov) * tanhfast(c0b);

            __hip_bfloat16 hb0 = __float2bfloat16(hn0), hb1 = __float2bfloat16(hn1);
            uint32_t pk = ((uint32_t)(*(uint16_t*)&hb1) << 16) | (uint32_t)(*(uint16_t*)&hb0);
            uint32_t nb = __shfl_down(pk, 4);

            // out partial for column t: reduce over q (lane bits 2-3)
            float pv = hn0 * wle + hn1 * wlo;
            pv += __shfl_xor(pv, 4);
            pv += __shfl_xor(pv, 8);

            if ((q_l & 1) == 0) {
                unsigned long long v = (unsigned long long)pk |
                                       ((unsigned long long)nb << 32);
                st64((unsigned long long*)
                     (h1w + (((t & 3) * NC + c) * 8 + (j - 8)) * 256 + row * 16 + wave * 4 + q_l), v);
            }
            if ((lane & 12) == 0)
                stf(op + ((((t & 3) * NC + c) * 32) + (j - 8) * 4 + wave) * 16 + row, pv);
            prefetch4(fL0a, fL0b, fL1a, fL1b, va, vb, vc, vd);
            drain_vmem();                    // per-wave: h + op acks + flags
            __syncthreads();
            if (tid == 0) st32((uint32_t*)myflag, (uint32_t)(t + 1));
        }
    }

    drain_vmem();

    // tail: columns TT-3..TT-1 by L0 WGs 5,6,7 (collective L1>=TT via waves)
    if (isL0 && j >= 5) {
        wave_poll_pf(fL0a, fL0b, fL1a, fL1b, 0, TT,
                     true, true, false, false, va, vb, vc, vd);
        __syncthreads();
        int col = TT - 8 + j, slot = col & 3;
        const float* o1 = op + (((slot * NC + c) * 32) + (tid & 15)) * 16 + (tid >> 4);
        float2 vv = ldf2_coh(o1, o1 + 256);
        float v = vv.x + vv.y;
        v += __shfl_down(v, 8, 16);
        v += __shfl_down(v, 4, 16);
        v += __shfl_down(v, 2, 16);
        v += __shfl_down(v, 1, 16);
        if ((tid & 15) == 0) out[(c * 16 + (tid >> 4)) * TT + col] = v + blin_r;
    }
}

extern "C" void kernel_launch(void* const* d_in, const int* in_sizes, int n_in,
                              void* d_out, int out_size, void* d_ws, size_t ws_size,
                              hipStream_t stream)
{
    const float* x    = (const float*)d_in[0];
    const float* Wih0 = (const float*)d_in[1];
    const float* Whh0 = (const float*)d_in[2];
    const float* bih0 = (const float*)d_in[3];
    const float* bhh0 = (const float*)d_in[4];
    const float* Wih1 = (const float*)d_in[5];
    const float* Whh1 = (const float*)d_in[6];
    const float* bih1 = (const float*)d_in[7];
    const float* bhh1 = (const float*)d_in[8];
    const float* Wlin = (const float*)d_in[9];
    const float* blin = (const float*)d_in[10];
    float* out = (float*)d_out;
    char* ws   = (char*)d_ws;

    // 256 blocks x 256 threads, 1 block/CU -> all co-resident (spin-safe).
    lstm_kernel<<<dim3(256), dim3(256), 0, stream>>>(
        x, Wih0, Whh0, bih0, bhh0, Wih1, Whh1, bih1, bhh1, Wlin, blin, out, ws);
}